// Round 4
// baseline (55.672 us; speedup 1.0000x reference)
//
#include <hip/hip_runtime.h>
#include <math.h>

#define NB 1024
#define IC 3
#define HW 32
#define GCH 16
#define ECH 32
#define NE 8
#define NC 100

// One block per sample. Patch is loaded DIRECTLY from global into registers
// (no LDS staging): global loads are not rematerializable, so the 54-float
// patch is forced to stay register-resident and the conv runs out of VGPRs.
__global__ __launch_bounds__(256, 4) void moe_fused_kernel(
    const float* __restrict__ x,     // [1024,3,32,32]
    const float* __restrict__ gcw,   // [16,3,3,3]
    const float* __restrict__ gcb,   // [16]
    const float* __restrict__ glw,   // [8,16]
    const float* __restrict__ glb,   // [8]
    const float* __restrict__ ecw,   // [8,32,3,3,3]
    const float* __restrict__ ecb,   // [8,32]
    const float* __restrict__ elw,   // [8,100,32]
    const float* __restrict__ elb,   // [8,100]
    float* __restrict__ out_final,   // [1024,100]
    float* __restrict__ out_w)       // [1024,8]
{
    __shared__ float red[4][ECH];
    __shared__ float pg[GCH];
    __shared__ float pe[ECH];
    __shared__ int s_best;

    const int t = threadIdx.x;
    const int b = blockIdx.x;
    const int lane = t & 63;
    const int wid = t >> 6;

    const int py = t >> 3;          // output row 0..31
    const int px0 = (t & 7) << 2;   // output col base 0,4,...,28

    // ---- per-thread 3x3x6 input patch, straight from global (L1-resident) ----
    float xr[IC][3][6];
    const float* xb = x + (size_t)b * (IC * HW * HW);
    #pragma unroll
    for (int ci = 0; ci < IC; ++ci) {
        const float* xc = xb + ci * (HW * HW);
        #pragma unroll
        for (int ky = 0; ky < 3; ++ky) {
            int row = py + ky - 1;
            bool rok = (row >= 0) && (row < HW);
            const float* xrow = xc + (rok ? row : 0) * HW;
            // all addresses clamped in-bounds; OOB values zeroed by cndmask
            float  l = xrow[px0 > 0 ? px0 - 1 : 0];
            float4 m = *(const float4*)(xrow + px0);   // 16B-aligned
            float  r = xrow[px0 + 4 < HW ? px0 + 4 : HW - 1];
            xr[ci][ky][0] = (rok && px0 > 0) ? l : 0.f;
            xr[ci][ky][1] = rok ? m.x : 0.f;
            xr[ci][ky][2] = rok ? m.y : 0.f;
            xr[ci][ky][3] = rok ? m.z : 0.f;
            xr[ci][ky][4] = rok ? m.w : 0.f;
            xr[ci][ky][5] = (rok && (px0 + 4 < HW)) ? r : 0.f;
        }
    }

    // ---- gate conv + relu + immediate per-channel pool reduce ----
    #pragma unroll 2
    for (int c = 0; c < GCH; ++c) {
        const float* w = gcw + c * 27;   // uniform -> s_load -> SGPR operands
        float p0 = 0.f, p1 = 0.f, p2 = 0.f, p3 = 0.f;
        #pragma unroll
        for (int ci = 0; ci < IC; ++ci)
            #pragma unroll
            for (int ky = 0; ky < 3; ++ky)
                #pragma unroll
                for (int kx = 0; kx < 3; ++kx) {
                    float wv = w[(ci * 3 + ky) * 3 + kx];
                    p0 += xr[ci][ky][kx + 0] * wv;
                    p1 += xr[ci][ky][kx + 1] * wv;
                    p2 += xr[ci][ky][kx + 2] * wv;
                    p3 += xr[ci][ky][kx + 3] * wv;
                }
        float bias = gcb[c];
        float v = fmaxf(p0 + bias, 0.f) + fmaxf(p1 + bias, 0.f) +
                  fmaxf(p2 + bias, 0.f) + fmaxf(p3 + bias, 0.f);
        #pragma unroll
        for (int off = 1; off < 64; off <<= 1) v += __shfl_xor(v, off);
        if (lane == 0) red[wid][c] = v;
    }
    __syncthreads();
    if (t < GCH)
        pg[t] = (red[0][t] + red[1][t] + red[2][t] + red[3][t]) * (1.f / 1024.f);
    __syncthreads();

    // ---- gate linear + softmax + argmax, lanes 0..7 of wave 0 ----
    if (t < NE) {
        float acc = glb[t];
        #pragma unroll
        for (int c = 0; c < GCH; ++c) acc += pg[c] * glw[t * GCH + c];
        float m = acc;
        #pragma unroll
        for (int off = 1; off < NE; off <<= 1) m = fmaxf(m, __shfl_xor(m, off));
        float ex = expf(acc - m);
        float s = ex;
        #pragma unroll
        for (int off = 1; off < NE; off <<= 1) s += __shfl_xor(s, off);
        out_w[(size_t)b * NE + t] = ex / s;
        float mv = acc; int mi = t;
        #pragma unroll
        for (int off = 1; off < NE; off <<= 1) {
            float ov = __shfl_xor(mv, off);
            int   oi = __shfl_xor(mi, off);
            if (ov > mv || (ov == mv && oi < mi)) { mv = ov; mi = oi; }
        }
        if (t == 0) s_best = mi;
    }
    __syncthreads();
    const int e = __builtin_amdgcn_readfirstlane(s_best);

    // ---- selected expert conv + relu + immediate per-channel pool reduce ----
    const float* ewp = ecw + (size_t)e * (ECH * 27);
    const float* ebp = ecb + (size_t)e * ECH;
    #pragma unroll 2
    for (int c = 0; c < ECH; ++c) {
        const float* w = ewp + c * 27;   // uniform -> s_load
        float p0 = 0.f, p1 = 0.f, p2 = 0.f, p3 = 0.f;
        #pragma unroll
        for (int ci = 0; ci < IC; ++ci)
            #pragma unroll
            for (int ky = 0; ky < 3; ++ky)
                #pragma unroll
                for (int kx = 0; kx < 3; ++kx) {
                    float wv = w[(ci * 3 + ky) * 3 + kx];
                    p0 += xr[ci][ky][kx + 0] * wv;
                    p1 += xr[ci][ky][kx + 1] * wv;
                    p2 += xr[ci][ky][kx + 2] * wv;
                    p3 += xr[ci][ky][kx + 3] * wv;
                }
        float bias = ebp[c];
        float v = fmaxf(p0 + bias, 0.f) + fmaxf(p1 + bias, 0.f) +
                  fmaxf(p2 + bias, 0.f) + fmaxf(p3 + bias, 0.f);
        #pragma unroll
        for (int off = 1; off < 64; off <<= 1) v += __shfl_xor(v, off);
        if (lane == 0) red[wid][c] = v;
    }
    __syncthreads();
    if (t < ECH)
        pe[t] = (red[0][t] + red[1][t] + red[2][t] + red[3][t]) * (1.f / 1024.f);
    __syncthreads();

    // ---- expert linear: 100 outputs ----
    if (t < NC) {
        const float* lw = elw + ((size_t)e * NC + t) * ECH;
        float acc = elb[e * NC + t];
        #pragma unroll
        for (int c = 0; c < ECH; ++c) acc += pe[c] * lw[c];
        out_final[(size_t)b * NC + t] = acc;
    }
}

extern "C" void kernel_launch(void* const* d_in, const int* in_sizes, int n_in,
                              void* d_out, int out_size, void* d_ws, size_t ws_size,
                              hipStream_t stream) {
    const float* x   = (const float*)d_in[0];
    const float* gcw = (const float*)d_in[1];
    const float* gcb = (const float*)d_in[2];
    const float* glw = (const float*)d_in[3];
    const float* glb = (const float*)d_in[4];
    const float* ecw = (const float*)d_in[5];
    const float* ecb = (const float*)d_in[6];
    const float* elw = (const float*)d_in[7];
    const float* elb = (const float*)d_in[8];

    float* out_final = (float*)d_out;             // [1024,100]
    float* out_w     = (float*)d_out + NB * NC;   // [1024,8]

    hipLaunchKernelGGL(moe_fused_kernel, dim3(NB), dim3(256), 0, stream,
                       x, gcw, gcb, glw, glb, ecw, ecb, elw, elb,
                       out_final, out_w);
}